// Round 4
// baseline (519.263 us; speedup 1.0000x reference)
//
#include <hip/hip_runtime.h>

typedef unsigned short u16;
typedef unsigned int u32;
using short8 = __attribute__((ext_vector_type(8))) short;
using f32x4  = __attribute__((ext_vector_type(4))) float;
using u16x4  = __attribute__((ext_vector_type(4))) u16;

#define D_MODEL 1024
#define NHEAD 16
#define DKV 64
#define TSEQ 2048
#define BATCH 2
#define L2E 1.44269504f
#define CSHIFT 12.0f

__device__ __forceinline__ u16 f2bf(float f) {      // RNE
    union { float f; u32 i; } c; c.f = f;
    u32 x = c.i;
    return (u16)((x + 0x7FFFu + ((x >> 16) & 1u)) >> 16);
}
__device__ __forceinline__ u16 f2bf_fast(float f) { // round-half-up (P only)
    union { float f; u32 i; } c; c.f = f;
    return (u16)((c.i + 0x8000u) >> 16);
}
// async global->LDS, 16B per lane. LDS dest semantics: wave-uniform base +
// lane*16 (m104/m108) — callers pass per-lane ptr equal to base + lane*16.
__device__ __forceinline__ void gl_lds16(const u16* g, u16* l) {
    __builtin_amdgcn_global_load_lds(
        (const __attribute__((address_space(1))) void*)g,
        (__attribute__((address_space(3))) void*)l, 16, 0, 0);
}

// ---------------------------------------------------------------------------
// Kernel 0: fp32 -> bf16 prep: [xbf 4.19M | wq wk wv wo 4x1.05M]
// ---------------------------------------------------------------------------
__global__ __launch_bounds__(256) void prep_cvt(
    const float* __restrict__ x,  const float* __restrict__ Wq,
    const float* __restrict__ Wk, const float* __restrict__ Wv,
    const float* __restrict__ Wo, u16* __restrict__ dst)
{
    size_t e = ((size_t)blockIdx.x * 256 + threadIdx.x) * 8;
    const float* src; size_t off;
    if (e < 4194304u)      { src = x;  off = e; }
    else if (e < 5242880u) { src = Wq; off = e - 4194304u; }
    else if (e < 6291456u) { src = Wk; off = e - 5242880u; }
    else if (e < 7340032u) { src = Wv; off = e - 6291456u; }
    else                   { src = Wo; off = e - 7340032u; }
    float4 a = *(const float4*)(src + off);
    float4 b = *(const float4*)(src + off + 4);
    short8 v;
    v[0] = (short)f2bf(a.x); v[1] = (short)f2bf(a.y);
    v[2] = (short)f2bf(a.z); v[3] = (short)f2bf(a.w);
    v[4] = (short)f2bf(b.x); v[5] = (short)f2bf(b.y);
    v[6] = (short)f2bf(b.z); v[7] = (short)f2bf(b.w);
    *(short8*)(dst + e) = v;
}

// ---------------------------------------------------------------------------
// Kernel 1: fused QKV projection, m97-style: global_load_lds staging into
// unpadded 128x64 tiles. V written pre-transposed [B,H,dk,T] (u16x4 stores).
// ---------------------------------------------------------------------------
__global__ __launch_bounds__(256) void qkv_gemm(
    const u16* __restrict__ xbf, const u16* __restrict__ wbf,
    const float* __restrict__ bq, const float* __restrict__ bk,
    const float* __restrict__ bv,
    u16* __restrict__ qws, u16* __restrict__ kws, u16* __restrict__ vtws)
{
    __shared__ __align__(16) u16 Alds[128 * 64];
    __shared__ __align__(16) u16 Blds[128 * 64];

    const int fid = blockIdx.x;
    const int xcd = fid & 7, ii = fid >> 3;       // ii 0..95
    const int z = ii >> 5, r2 = ii & 31;
    const int nb = r2 & 7, mb = xcd * 4 + (r2 >> 3);
    const int n0 = nb * 128, m0 = mb * 128;
    const u16* W = wbf + (size_t)z * 1048576;

    const int t = threadIdx.x;
    const int wave = t >> 6, lane = t & 63, l15 = lane & 15, quad = lane >> 4;
    const int wm = (wave >> 1) * 64, wn = (wave & 1) * 64;
    const int lrow = lane >> 3, lcol = (lane & 7) * 8;

    f32x4 acc[4][4];
#pragma unroll
    for (int i = 0; i < 4; ++i)
#pragma unroll
        for (int j = 0; j < 4; ++j)
#pragma unroll
            for (int r = 0; r < 4; ++r) acc[i][j][r] = 0.f;

    for (int kt = 0; kt < 16; ++kt) {
        const int k0 = kt * 64;
#pragma unroll
        for (int ra = 0; ra < 4; ++ra) {
            int row0 = ra * 32 + wave * 8;
            gl_lds16(&xbf[(size_t)(m0 + row0 + lrow) * 1024 + k0 + lcol],
                     &Alds[row0 * 64 + lane * 8]);
            gl_lds16(&W[(size_t)(n0 + row0 + lrow) * 1024 + k0 + lcol],
                     &Blds[row0 * 64 + lane * 8]);
        }
        __syncthreads();
#pragma unroll
        for (int ki = 0; ki < 2; ++ki) {
            short8 af[4], bfr[4];
#pragma unroll
            for (int i = 0; i < 4; ++i)
                af[i] = *(const short8*)&Alds[(wm + i * 16 + l15) * 64 + ki * 32 + quad * 8];
#pragma unroll
            for (int j = 0; j < 4; ++j)
                bfr[j] = *(const short8*)&Blds[(wn + j * 16 + l15) * 64 + ki * 32 + quad * 8];
#pragma unroll
            for (int i = 0; i < 4; ++i)
#pragma unroll
                for (int j = 0; j < 4; ++j)
                    acc[i][j] = __builtin_amdgcn_mfma_f32_16x16x32_bf16(af[i], bfr[j], acc[i][j], 0, 0, 0);
        }
        __syncthreads();
    }

    const float* bias = (z == 0) ? bq : (z == 1) ? bk : bv;
    if (z < 2) {
        u16* out = (z == 0) ? qws : kws;
#pragma unroll
        for (int j = 0; j < 4; ++j) {
            int n = n0 + wn + j * 16 + l15;
            float bb = bias[n];
            int h = n >> 6, d = n & 63;
#pragma unroll
            for (int i = 0; i < 4; ++i)
#pragma unroll
                for (int r = 0; r < 4; ++r) {
                    int m = m0 + wm + i * 16 + quad * 4 + r;
                    int bidx = m >> 11, tt = m & 2047;
                    out[(((size_t)(bidx * NHEAD + h)) * TSEQ + tt) * DKV + d] =
                        f2bf(acc[i][j][r] + bb);
                }
        }
    } else {
        // V^T [B,H,dk,T]: r=0..3 are consecutive tt at fixed d -> u16x4 store
#pragma unroll
        for (int j = 0; j < 4; ++j) {
            int n = n0 + wn + j * 16 + l15;
            float bb = bias[n];
            int h = n >> 6, d = n & 63;
#pragma unroll
            for (int i = 0; i < 4; ++i) {
                int m = m0 + wm + i * 16 + quad * 4;
                int bidx = m >> 11, tt = m & 2047;
                u16x4 pv;
#pragma unroll
                for (int r = 0; r < 4; ++r) pv[r] = f2bf(acc[i][j][r] + bb);
                *(u16x4*)&vtws[((size_t)(bidx * NHEAD + h) * DKV + d) * TSEQ + tt] = pv;
            }
        }
    }
}

// ---------------------------------------------------------------------------
// Kernel 2: flash attention, fixed-shift softmax. K and V^T staged via
// global_load_lds (unpadded). Vt double-buffered. Batch-twin blocks adjacent
// in the same XCD stream so the shared bias tile hits L2.
// ---------------------------------------------------------------------------
__global__ __launch_bounds__(256) void attn_kernel(
    const u16* __restrict__ qws, const u16* __restrict__ kws,
    const u16* __restrict__ vtws, const float* __restrict__ bias,
    u16* __restrict__ ows)
{
    __shared__ __align__(16) u16 Klds[64 * 64];
    __shared__ __align__(16) u16 Vt[2][64 * 64];
    __shared__ __align__(16) u16 Plds[64 * 72];

    const int fid = blockIdx.x;
    const int xcd = fid & 7, ii = fid >> 3;   // ii 0..127
    const int b = ii & 1, j = ii >> 1;        // twins (b=0/1) adjacent per XCD
    const int qt = j & 31, h = xcd * 2 + (j >> 5);
    const int bh = b * NHEAD + h;
    const int q0 = qt * 64;
    const int t = threadIdx.x;
    const int wave = t >> 6, lane = t & 63, l15 = lane & 15, quad = lane >> 4;
    const size_t bhoff = (size_t)bh * TSEQ * DKV;

    short8 qa0, qa1;
    {
        const u16* qp = qws + bhoff + (size_t)(q0 + wave * 16 + l15) * DKV;
        qa0 = *(const short8*)(qp + quad * 8);
        qa1 = *(const short8*)(qp + 32 + quad * 8);
    }

    float l_run[4] = {0.f, 0.f, 0.f, 0.f};
    f32x4 o_acc[4];
#pragma unroll
    for (int db = 0; db < 4; ++db)
#pragma unroll
        for (int r = 0; r < 4; ++r) o_acc[db][r] = 0.f;

    const float* bias_h = bias + ((size_t)h * TSEQ + q0) * TSEQ;
    const int lrow = lane >> 3, lcol = (lane & 7) * 8;
    const int rbase = wave * 16 + quad * 4;

    for (int kt = 0; kt < TSEQ / 64; ++kt) {
        const int kc0 = kt * 64;
        u16* vtb = &Vt[kt & 1][0];

        // async stage K [kc][d] and V^T [d][kc]
#pragma unroll
        for (int rr = 0; rr < 2; ++rr) {
            int row0 = rr * 32 + wave * 8;
            gl_lds16(&kws[bhoff + (size_t)(kc0 + row0 + lrow) * DKV + lcol],
                     &Klds[row0 * 64 + lane * 8]);
            gl_lds16(&vtws[bhoff + (size_t)(row0 + lrow) * TSEQ + kc0 + lcol],
                     &vtb[row0 * 64 + lane * 8]);
        }
        // bias tile -> registers (C-layout), overlaps async staging
        float bz[16];
#pragma unroll
        for (int cb = 0; cb < 4; ++cb)
#pragma unroll
            for (int r = 0; r < 4; ++r)
                bz[cb * 4 + r] =
                    bias_h[(size_t)(rbase + r) * TSEQ + kc0 + cb * 16 + l15];
        __syncthreads();

        // S = Q K^T
        f32x4 s[4];
#pragma unroll
        for (int cb = 0; cb < 4; ++cb)
#pragma unroll
            for (int r = 0; r < 4; ++r) s[cb][r] = 0.f;
#pragma unroll
        for (int cb = 0; cb < 4; ++cb) {
            const u16* kr = &Klds[(cb * 16 + l15) * 64 + quad * 8];
            short8 kb0 = *(const short8*)kr;
            short8 kb1 = *(const short8*)(kr + 32);
            s[cb] = __builtin_amdgcn_mfma_f32_16x16x32_bf16(qa0, kb0, s[cb], 0, 0, 0);
            s[cb] = __builtin_amdgcn_mfma_f32_16x16x32_bf16(qa1, kb1, s[cb], 0, 0, 0);
        }

        // p = exp2(log2e*(s/8 + bias) - C') ; accumulate l; P -> LDS
#pragma unroll
        for (int cb = 0; cb < 4; ++cb)
#pragma unroll
            for (int r = 0; r < 4; ++r) {
                float arg = fmaf(s[cb][r], 0.125f * L2E,
                                 fmaf(bz[cb * 4 + r], L2E, -CSHIFT * L2E));
                float p = exp2f(fminf(arg, 43.f));
                l_run[r] += p;
                Plds[(rbase + r) * 72 + cb * 16 + l15] = f2bf_fast(p);
            }
        __syncthreads();

        // PV: O += P V
        {
            const u16* pr = &Plds[(wave * 16 + l15) * 72 + quad * 8];
            short8 pa0 = *(const short8*)pr;
            short8 pa1 = *(const short8*)(pr + 32);
#pragma unroll
            for (int db = 0; db < 4; ++db) {
                const u16* vr = &vtb[(db * 16 + l15) * 64 + quad * 8];
                short8 vb0 = *(const short8*)vr;
                short8 vb1 = *(const short8*)(vr + 32);
                o_acc[db] = __builtin_amdgcn_mfma_f32_16x16x32_bf16(pa0, vb0, o_acc[db], 0, 0, 0);
                o_acc[db] = __builtin_amdgcn_mfma_f32_16x16x32_bf16(pa1, vb1, o_acc[db], 0, 0, 0);
            }
        }
    }

#pragma unroll
    for (int r = 0; r < 4; ++r) {
        float v = l_run[r];
        v += __shfl_xor(v, 1);
        v += __shfl_xor(v, 2);
        v += __shfl_xor(v, 4);
        v += __shfl_xor(v, 8);
        l_run[r] = v;
    }
#pragma unroll
    for (int r = 0; r < 4; ++r) {
        float inv = 1.f / l_run[r];
        int row = q0 + rbase + r;
#pragma unroll
        for (int db = 0; db < 4; ++db)
            ows[bhoff + (size_t)row * DKV + db * 16 + l15] = f2bf(o_acc[db][r] * inv);
    }
}

// ---------------------------------------------------------------------------
// Kernel 3: output projection, m97-style staging. A read head-wise from
// [B,H,T,dk] ws (BK=64 == one head).
// ---------------------------------------------------------------------------
__global__ __launch_bounds__(256) void out_gemm(
    const u16* __restrict__ ows, const u16* __restrict__ wobf,
    const float* __restrict__ bo, float* __restrict__ out)
{
    __shared__ __align__(16) u16 Alds[128 * 64];
    __shared__ __align__(16) u16 Blds[128 * 64];

    const int fid = blockIdx.x;
    const int xcd = fid & 7, ii = fid >> 3;     // ii 0..31
    const int nb = ii & 7, mb = xcd * 4 + (ii >> 3);
    const int n0 = nb * 128, m0 = mb * 128;

    const int t = threadIdx.x;
    const int wave = t >> 6, lane = t & 63, l15 = lane & 15, quad = lane >> 4;
    const int wm = (wave >> 1) * 64, wn = (wave & 1) * 64;
    const int lrow = lane >> 3, lcol = (lane & 7) * 8;

    f32x4 acc[4][4];
#pragma unroll
    for (int i = 0; i < 4; ++i)
#pragma unroll
        for (int j = 0; j < 4; ++j)
#pragma unroll
            for (int r = 0; r < 4; ++r) acc[i][j][r] = 0.f;

    for (int kt = 0; kt < 16; ++kt) {
        const int k0 = kt * 64;
#pragma unroll
        for (int ra = 0; ra < 4; ++ra) {
            int row0 = ra * 32 + wave * 8;
            int m = m0 + row0 + lrow;
            int bidx = m >> 11, tt = m & 2047;
            gl_lds16(&ows[(((size_t)(bidx * NHEAD + kt)) * TSEQ + tt) * DKV + lcol],
                     &Alds[row0 * 64 + lane * 8]);
            gl_lds16(&wobf[(size_t)(n0 + row0 + lrow) * 1024 + k0 + lcol],
                     &Blds[row0 * 64 + lane * 8]);
        }
        __syncthreads();
#pragma unroll
        for (int ki = 0; ki < 2; ++ki) {
            short8 af[4], bfr[4];
#pragma unroll
            for (int i = 0; i < 4; ++i)
                af[i] = *(const short8*)&Alds[(wm + i * 16 + l15) * 64 + ki * 32 + quad * 8];
#pragma unroll
            for (int j = 0; j < 4; ++j)
                bfr[j] = *(const short8*)&Blds[(wn + j * 16 + l15) * 64 + ki * 32 + quad * 8];
#pragma unroll
            for (int i = 0; i < 4; ++i)
#pragma unroll
                for (int j = 0; j < 4; ++j)
                    acc[i][j] = __builtin_amdgcn_mfma_f32_16x16x32_bf16(af[i], bfr[j], acc[i][j], 0, 0, 0);
        }
        __syncthreads();
    }

#pragma unroll
    for (int j = 0; j < 4; ++j) {
        int n = n0 + wn + j * 16 + l15;
        float bb = bo[n];
#pragma unroll
        for (int i = 0; i < 4; ++i)
#pragma unroll
            for (int r = 0; r < 4; ++r) {
                int m = m0 + wm + i * 16 + quad * 4 + r;
                out[(size_t)m * 1024 + n] = acc[i][j][r] + bb;
            }
    }
}

extern "C" void kernel_launch(void* const* d_in, const int* in_sizes, int n_in,
                              void* d_out, int out_size, void* d_ws, size_t ws_size,
                              hipStream_t stream)
{
    const float* x  = (const float*)d_in[0];
    const float* ab = (const float*)d_in[1];
    const float* Wq = (const float*)d_in[2];
    const float* bq = (const float*)d_in[3];
    const float* Wk = (const float*)d_in[4];
    const float* bk = (const float*)d_in[5];
    const float* Wv = (const float*)d_in[6];
    const float* bv = (const float*)d_in[7];
    const float* Wo = (const float*)d_in[8];
    const float* bo = (const float*)d_in[9];
    float* out = (float*)d_out;

    u16* wsu = (u16*)d_ws;
    // ws (u16): [0 xbf 4.19M | 4.19M W 4x1.05M | 8.39M q | 12.58M k |
    //            16.78M vt | 20.97M o]  -> 50 MB
    const size_t WBF = 4194304;
    const size_t QWS = 8388608;
    const size_t KWS = 12582912;
    const size_t VTW = 16777216;
    const size_t OWS = 20971520;

    prep_cvt<<<4096, 256, 0, stream>>>(x, Wq, Wk, Wv, Wo, wsu);
    qkv_gemm<<<768, 256, 0, stream>>>(wsu, wsu + WBF, bq, bk, bv,
                                      wsu + QWS, wsu + KWS, wsu + VTW);
    attn_kernel<<<1024, 256, 0, stream>>>(wsu + QWS, wsu + KWS, wsu + VTW,
                                          ab, wsu + OWS);
    out_gemm<<<256, 256, 0, stream>>>(wsu + OWS, wsu + WBF + 3 * 1048576, bo, out);
}